// Round 10
// baseline (382.703 us; speedup 1.0000x reference)
//
#include <hip/hip_runtime.h>
#include <stdint.h>

typedef unsigned short u16;
typedef __attribute__((ext_vector_type(4))) float    floatx4;
typedef __attribute__((ext_vector_type(8))) __bf16   bf16x8;
typedef __attribute__((ext_vector_type(2))) unsigned int uintx2;
typedef __attribute__((ext_vector_type(4))) unsigned int uintx4;

__device__ inline u16 f2bf(float f) {            // RNE float->bf16
  unsigned int u = __builtin_bit_cast(unsigned int, f);
  u += 0x7fffu + ((u >> 16) & 1u);
  return (u16)(u >> 16);
}

#define GLD16(gsrc, ldst)                                                        \
  __builtin_amdgcn_global_load_lds(                                              \
      (__attribute__((address_space(1))) void*)(gsrc),                           \
      (__attribute__((address_space(3))) void*)(ldst), 16, 0, 0)

#define SB() __builtin_amdgcn_sched_barrier(0)

// ---------------------------------------------------------------------------
// combined prep: z<3 -> transpose-cast W_z into WT; z>=3 -> cast x -> bf16
__global__ __launch_bounds__(256) void prep_kernel(const float* __restrict__ x,
                                                   const float* __restrict__ Wq,
                                                   const float* __restrict__ Wk,
                                                   const float* __restrict__ Wv,
                                                   u16* __restrict__ xb,
                                                   u16* __restrict__ WT) {
  const int z = blockIdx.z;
  const int tid = threadIdx.y * 32 + threadIdx.x;
  if (z >= 3) {   // cast x chunk
    long blk = (long)(z - 3) * 1024 + blockIdx.y * 32 + blockIdx.x;
    long i = (blk * 256 + tid) * 8;
    floatx4 a = *(const floatx4*)(x + i);
    floatx4 b = *(const floatx4*)(x + i + 4);
    uintx4 o;
    o[0] = (unsigned)f2bf(a[0]) | ((unsigned)f2bf(a[1]) << 16);
    o[1] = (unsigned)f2bf(a[2]) | ((unsigned)f2bf(a[3]) << 16);
    o[2] = (unsigned)f2bf(b[0]) | ((unsigned)f2bf(b[1]) << 16);
    o[3] = (unsigned)f2bf(b[2]) | ((unsigned)f2bf(b[3]) << 16);
    *(uintx4*)(xb + i) = o;
    return;
  }
  __shared__ float tile[32][33];
  const float* W = (z == 0) ? Wq : (z == 1) ? Wk : Wv;
  u16* dst = WT + (long)z * 1024 * 1024;
  int bx = blockIdx.x * 32, by = blockIdx.y * 32;
  int tx = threadIdx.x, ty = threadIdx.y;                 // 32 x 8
  for (int i = 0; i < 32; i += 8)
    tile[ty + i][tx] = W[(long)(by + ty + i) * 1024 + bx + tx];
  __syncthreads();
  for (int i = 0; i < 32; i += 8)
    dst[(long)(bx + ty + i) * 1024 + by + tx] = f2bf(tile[tx][ty + i]);
}

// ---------------------------------------------------------------------------
// gemm_bt: C[m][n] = sum_k A[m][k] * Bt[n][k]   (A, Bt bf16, lda=ldb=K)
// UNPINNED ROUND: r9 skeleton (256x256, BK=64, 1024 thr = 16 waves 4Mx4N,
// acc[4][4], 4 waves/SIMD, counted-vmcnt 2-phase double buffer) with the
// compute section UNPINNED. r1-r9 all placed `lgkmcnt(0)+sched_barrier`
// between the fragment ds_reads and the MFMA cluster — forcing every wave
// to drain the whole LDS queue before any MFMA issues. Per-CU arithmetic:
// LDS port work ~2-3k cyc + MFMA 2355 cyc; measured 6300 = their SUM ->
// the pins globally serialized [all-read][all-MFMA] bursts (MfmaUtil
// 2355/6300 = 37%, matching all 9 rounds). m97 (874 TF, no pins) lets the
// compiler emit partial lgkmcnt(4/3/1/0) so MFMA starts while later reads
// drain. This round: reads + MFMAs are plain code, NO lgkm pins, NO
// sched_barrier, NO setprio between them. Retained pins: SB after each
// s_barrier (stops read-hoist above the DMA-visibility barrier), a ~free
// lgkm(0) before the overwrite barrier (reads already consumed), and r9's
// exact vmcnt ledger:
//   prologue: stage t0,t1; vmcnt(4) [t0 landed]; barrier.
//   iter t: [reads+MFMAs, compiler-scheduled]; lgkm(0); BARRIER; stage
//           (t+2 -> buf[cur]); vmcnt(4) if t+2<=nt-1 else vmcnt(0) if
//           t+1==nt-1; BARRIER.
// Addressing/swizzle identical (0 conflicts verified).
// MODE 0: merged q|k projection; MODE 1: vT scatter; MODE 2: exp+rowsum;
// MODE 3: fp32 / lsum[row].
#define BM 256
#define BN 256
#define BK 64

template <int MODE, int GN>
__global__ __launch_bounds__(1024, 4)
void gemm_bt(const u16* __restrict__ Aall, const u16* __restrict__ Ball,
             void* __restrict__ Call, void* __restrict__ C2,
             const float* __restrict__ bias, const float* __restrict__ bias2,
             float* __restrict__ lsum,
             int M, int N, int K, long aStride, long bStride, long cStride) {
  __shared__ __align__(16) u16 As[2][BM * BK];   // 2 x 32 KB
  __shared__ __align__(16) u16 Bs[2][BN * BK];   // 2 x 32 KB

  const int z = blockIdx.z;
  const u16* A  = Aall + (long)z * aStride;
  const u16* Bt = Ball + (long)z * bStride;

  // XCD-chunked bijective swizzle, then GN grouping
  int m_idx, n_idx;
  {
    const int tiles_n = gridDim.x, tiles_m = gridDim.y;
    int nwg = tiles_n * tiles_m;
    int bid = blockIdx.y * tiles_n + blockIdx.x;
    int qq = nwg >> 3;                       // all grids are %8 == 0
    int L = (bid & 7) * qq + (bid >> 3);
    int per_group = GN * tiles_m;
    int g = L / per_group;
    int rem = L - g * per_group;
    n_idx = g * GN + rem % GN;
    m_idx = rem / GN;
  }

  const int tid  = threadIdx.x;
  const int m0   = m_idx * BM;
  const int n0   = n_idx * BN;
  const int wave = tid >> 6;             // 0..15
  const int lane = tid & 63;
  const int wm   = (wave >> 2) * 64;     // wave row offset (4 waves in M)
  const int wn   = (wave & 3) * 64;      // wave col offset (4 waves in N)
  const int l15  = lane & 15;
  const int quad = lane >> 4;

  floatx4 acc[4][4];
  floatx4 zero = {0.f, 0.f, 0.f, 0.f};
#pragma unroll
  for (int i = 0; i < 4; ++i)
#pragma unroll
    for (int j = 0; j < 4; ++j) acc[i][j] = zero;

  // LDS read offsets (u16), loop-invariant. slot = (ks*4+quad)^(r&7),
  // r&7 == l15&7 (wm,wn,mi*16 all 0 mod 8); ks1 = ks0 ^ 32 (u16).
  const int swz   = (quad ^ (l15 & 7)) * 8;
  const int aOff0 = (wm + l15) * 64 + swz;
  const int bOff0 = (wn + l15) * 64 + swz;

  // staging: unit u in {A0,A1,B0,B1}; chunk ci = u*1024+tid -> row r=ci>>3
  // (128 rows/unit), slot sc=ci&7 holds source k-chunk sc^(r&7)
  // (source-swizzle, rule #21; identical algebra to r4/r9).
  const u16* gA[2];
  const u16* gB[2];
#pragma unroll
  for (int i = 0; i < 2; ++i) {
    int ci = i * 1024 + tid;
    int r = ci >> 3, sc = ci & 7;
    int col = (sc ^ (r & 7)) * 8;
    gA[i] = A  + (long)(m0 + r) * K + col;
    gB[i] = Bt + (long)(n0 + r) * K + col;
  }

  const int nt = K / BK;            // 16 or 32 here

  // prologue: stage tile 0 -> buf0, tile 1 -> buf1; force tile 0; barrier.
  {
    u16* lA = (u16*)As + tid * 8;
    u16* lB = (u16*)Bs + tid * 8;
    GLD16(gA[0], lA); GLD16(gA[1], lA + 8192);
    GLD16(gB[0], lB); GLD16(gB[1], lB + 8192);
    GLD16(gA[0] + BK, lA + 16384); GLD16(gA[1] + BK, lA + 24576);
    GLD16(gB[0] + BK, lB + 16384); GLD16(gB[1] + BK, lB + 24576);
  }
  SB();
  asm volatile("s_waitcnt vmcnt(4)" ::: "memory");   // tile 0 landed
  SB();
  __builtin_amdgcn_s_barrier();
  SB();
#pragma unroll
  for (int i = 0; i < 2; ++i) { gA[i] += 2 * BK; gB[i] += 2 * BK; }

  for (int t = 0; t < nt; ++t) {
    const int bo  = (t & 1) << 14;                   // cur * 16384 u16 (32 KB)
    const u16* aP0 = (const u16*)As + bo + aOff0;          // ks0 base
    const u16* bP0 = (const u16*)Bs + bo + bOff0;
    const u16* aP1 = (const u16*)As + bo + (aOff0 ^ 32);   // ks1 base
    const u16* bP1 = (const u16*)Bs + bo + (bOff0 ^ 32);
    u16* ldsA = (u16*)As + bo + tid * 8;             // cur-buffer dests (t+2)
    u16* ldsB = (u16*)Bs + bo + tid * 8;
    bf16x8 af0[4], bfr0[4], af1[4], bfr1[4];

    // ---- UNPINNED compute: compiler interleaves ds_read <-> MFMA with
    // partial lgkmcnt waits (the m97 mechanism). No pins, no setprio. ----
#pragma unroll
    for (int mi = 0; mi < 4; ++mi)
      af0[mi] = *(const bf16x8*)(aP0 + mi * 1024);
#pragma unroll
    for (int ni = 0; ni < 4; ++ni)
      bfr0[ni] = *(const bf16x8*)(bP0 + ni * 1024);
#pragma unroll
    for (int mi = 0; mi < 4; ++mi)
#pragma unroll
      for (int ni = 0; ni < 4; ++ni)
        acc[mi][ni] = __builtin_amdgcn_mfma_f32_16x16x32_bf16(
            bfr0[ni], af0[mi], acc[mi][ni], 0, 0, 0);   // swapped operands
#pragma unroll
    for (int mi = 0; mi < 4; ++mi)
      af1[mi] = *(const bf16x8*)(aP1 + mi * 1024);
#pragma unroll
    for (int ni = 0; ni < 4; ++ni)
      bfr1[ni] = *(const bf16x8*)(bP1 + ni * 1024);
#pragma unroll
    for (int mi = 0; mi < 4; ++mi)
#pragma unroll
      for (int ni = 0; ni < 4; ++ni)
        acc[mi][ni] = __builtin_amdgcn_mfma_f32_16x16x32_bf16(
            bfr1[ni], af1[mi], acc[mi][ni], 0, 0, 0);

    // all fragment reads were consumed by the MFMAs above -> this drain is
    // ~free; it guarantees no wave still reads buf[cur] past the barrier.
    asm volatile("s_waitcnt lgkmcnt(0)" ::: "memory");
    __builtin_amdgcn_s_barrier();   // all waves done reading buf[cur]
    SB();
    if (t + 2 < nt) {
      GLD16(gA[0], ldsA); GLD16(gA[1], ldsA + 8192);
      GLD16(gB[0], ldsB); GLD16(gB[1], ldsB + 8192);
#pragma unroll
      for (int i = 0; i < 2; ++i) { gA[i] += BK; gB[i] += BK; }
    }
    SB();
    // force tile t+1 before the barrier that opens iteration t+1 (r9 ledger)
    if (t + 2 <= nt - 1)      asm volatile("s_waitcnt vmcnt(4)" ::: "memory");
    else if (t + 1 == nt - 1) asm volatile("s_waitcnt vmcnt(0)" ::: "memory");
    SB();
    __builtin_amdgcn_s_barrier();
    SB();   // iteration t+1's ds_reads must not hoist above this barrier
  }

  // epilogue (swapped D layout): row(m) = l15-based, 4 regs = 4 consecutive n-cols
#pragma unroll
  for (int mi = 0; mi < 4; ++mi) {
    const int row = m0 + wm + mi * 16 + l15;      // fixed per lane
    if (MODE == 2) {
      u16* C = (u16*)Call + (long)z * cStride;
      float rs = 0.f;
#pragma unroll
      for (int ni = 0; ni < 4; ++ni) {
        int colb = n0 + wn + ni * 16 + quad * 4;
        floatx4 v = acc[mi][ni];
        float e0 = __expf(v[0] * 0.03125f), e1 = __expf(v[1] * 0.03125f);
        float e2 = __expf(v[2] * 0.03125f), e3 = __expf(v[3] * 0.03125f);
        rs += (e0 + e1) + (e2 + e3);
        uintx2 o;
        o[0] = (unsigned)f2bf(e0) | ((unsigned)f2bf(e1) << 16);
        o[1] = (unsigned)f2bf(e2) | ((unsigned)f2bf(e3) << 16);
        *(uintx2*)(C + (long)row * N + colb) = o;
      }
      rs += __shfl_xor(rs, 16);
      rs += __shfl_xor(rs, 32);
      if (quad == 0) atomicAdd(lsum + (long)z * 2048 + row, rs);
    } else if (MODE == 3) {
      float* C = (float*)Call + (long)z * cStride;
      float inv = 1.0f / lsum[(long)z * 2048 + row];
#pragma unroll
      for (int ni = 0; ni < 4; ++ni) {
        int colb = n0 + wn + ni * 16 + quad * 4;
        floatx4 v = acc[mi][ni];
        floatx4 o = {v[0] * inv, v[1] * inv, v[2] * inv, v[3] * inv};
        *(floatx4*)(C + (long)row * N + colb) = o;
      }
    } else if (MODE == 0) {
#pragma unroll
      for (int ni = 0; ni < 4; ++ni) {
        int colb = n0 + wn + ni * 16 + quad * 4;
        u16* C = (colb < 1024) ? (u16*)Call : (u16*)C2;
        const float* bp = (colb < 1024) ? bias + colb : bias2 + (colb - 1024);
        floatx4 b = *(const floatx4*)bp;
        floatx4 v = acc[mi][ni];
        uintx2 o;
        o[0] = (unsigned)f2bf(v[0] + b[0]) | ((unsigned)f2bf(v[1] + b[1]) << 16);
        o[1] = (unsigned)f2bf(v[2] + b[2]) | ((unsigned)f2bf(v[3] + b[3]) << 16);
        *(uintx2*)(C + (long)row * 1024 + (colb & 1023)) = o;
      }
    } else {  // MODE 1: vT scatter — row=do, cols=4 consecutive t
      u16* C = (u16*)Call;
      float b = bias[row];
#pragma unroll
      for (int ni = 0; ni < 4; ++ni) {
        int colb = n0 + wn + ni * 16 + quad * 4;   // global t index over B*T
        long base = ((long)(colb >> 11) * 1024) * 2048 + (colb & 2047);
        floatx4 v = acc[mi][ni];
        uintx2 o;
        o[0] = (unsigned)f2bf(v[0] + b) | ((unsigned)f2bf(v[1] + b) << 16);
        o[1] = (unsigned)f2bf(v[2] + b) | ((unsigned)f2bf(v[3] + b) << 16);
        *(uintx2*)(C + base + (long)row * 2048) = o;
      }
    }
  }
}

// ---------------------------------------------------------------------------
extern "C" void kernel_launch(void* const* d_in, const int* in_sizes, int n_in,
                              void* d_out, int out_size, void* d_ws, size_t ws_size,
                              hipStream_t stream) {
  const float* x  = (const float*)d_in[0];
  const float* Wq = (const float*)d_in[1];
  const float* bq = (const float*)d_in[2];
  const float* Wk = (const float*)d_in[3];
  const float* bk = (const float*)d_in[4];
  const float* Wv = (const float*)d_in[5];
  const float* bv = (const float*)d_in[6];
  float* out = (float*)d_out;

  const long BT = 16384;   // B*T
  u16* xb = (u16*)d_ws;                    // [16384,1024] bf16   32 MB
  u16* WT = xb + BT * 1024;                // [3][1024,1024]       6 MB
  u16* qb = WT + 3L * 1024 * 1024;         // [16384,1024]        32 MB
  u16* kb = qb + BT * 1024;                // [16384,1024]        32 MB
  u16* vT = kb + BT * 1024;                // [8][1024][2048]     32 MB
  u16* S  = vT + BT * 1024;                // [8][2048][2048]     64 MB
  float* lsum = (float*)(S + 8L * 2048 * 2048);   // [8][2048]    64 KB

  hipMemsetAsync(lsum, 0, 8 * 2048 * sizeof(float), stream);

  // z 0..2: transpose-cast W; z 3..10: cast x
  prep_kernel<<<dim3(32, 32, 11), dim3(32, 8), 0, stream>>>(x, Wq, Wk, Wv, xb, WT);

  // q|k = x [Wq|Wk] + [bq|bk]   (WT rows 0..2047 are Wq^T then Wk^T)
  gemm_bt<0, 8><<<dim3(8, 64, 1), 1024, 0, stream>>>(
      xb, WT, qb, kb, bq, bk, nullptr, 16384, 2048, 1024, 0, 0, 0);
  // vT[b][do][t] = (Wv^T x^T + bv) : A=WvT [1024,1024], Bt=xb [16384,1024]
  gemm_bt<1, 8><<<dim3(64, 4, 1), 1024, 0, stream>>>(
      WT + 2L * 1024 * 1024, xb, vT, nullptr, bv, nullptr, nullptr,
      1024, 16384, 1024, 0, 0, 0);
  // E[b] = exp(q_b k_b^T / 32), row-sums -> lsum
  gemm_bt<2, 8><<<dim3(8, 8, 8), 1024, 0, stream>>>(
      qb, kb, S, nullptr, nullptr, nullptr, lsum,
      2048, 2048, 1024, 2048L * 1024, 2048L * 1024, 2048L * 2048);
  // out[b] = (E_b V_b) / lsum : A=E [2048,2048], Bt=vT_b [1024,2048]
  gemm_bt<3, 4><<<dim3(4, 8, 8), 1024, 0, stream>>>(
      S, vT, out, nullptr, nullptr, nullptr, lsum,
      2048, 1024, 2048, 2048L * 2048, 1024L * 2048, 2048L * 1024);
}

// Round 11
// 374.061 us; speedup vs baseline: 1.0231x; 1.0231x over previous
//
#include <hip/hip_runtime.h>
#include <stdint.h>

typedef unsigned short u16;
typedef __attribute__((ext_vector_type(4))) float    floatx4;
typedef __attribute__((ext_vector_type(8))) __bf16   bf16x8;
typedef __attribute__((ext_vector_type(2))) unsigned int uintx2;
typedef __attribute__((ext_vector_type(4))) unsigned int uintx4;

__device__ inline u16 f2bf(float f) {            // RNE float->bf16
  unsigned int u = __builtin_bit_cast(unsigned int, f);
  u += 0x7fffu + ((u >> 16) & 1u);
  return (u16)(u >> 16);
}

#define GLD16(gsrc, ldst)                                                        \
  __builtin_amdgcn_global_load_lds(                                              \
      (__attribute__((address_space(1))) void*)(gsrc),                           \
      (__attribute__((address_space(3))) void*)(ldst), 16, 0, 0)

#define SB() __builtin_amdgcn_sched_barrier(0)

// ---------------------------------------------------------------------------
// combined prep: z<3 -> transpose-cast W_z into WT; z>=3 -> cast x -> bf16
__global__ __launch_bounds__(256) void prep_kernel(const float* __restrict__ x,
                                                   const float* __restrict__ Wq,
                                                   const float* __restrict__ Wk,
                                                   const float* __restrict__ Wv,
                                                   u16* __restrict__ xb,
                                                   u16* __restrict__ WT) {
  const int z = blockIdx.z;
  const int tid = threadIdx.y * 32 + threadIdx.x;
  if (z >= 3) {   // cast x chunk
    long blk = (long)(z - 3) * 1024 + blockIdx.y * 32 + blockIdx.x;
    long i = (blk * 256 + tid) * 8;
    floatx4 a = *(const floatx4*)(x + i);
    floatx4 b = *(const floatx4*)(x + i + 4);
    uintx4 o;
    o[0] = (unsigned)f2bf(a[0]) | ((unsigned)f2bf(a[1]) << 16);
    o[1] = (unsigned)f2bf(a[2]) | ((unsigned)f2bf(a[3]) << 16);
    o[2] = (unsigned)f2bf(b[0]) | ((unsigned)f2bf(b[1]) << 16);
    o[3] = (unsigned)f2bf(b[2]) | ((unsigned)f2bf(b[3]) << 16);
    *(uintx4*)(xb + i) = o;
    return;
  }
  __shared__ float tile[32][33];
  const float* W = (z == 0) ? Wq : (z == 1) ? Wk : Wv;
  u16* dst = WT + (long)z * 1024 * 1024;
  int bx = blockIdx.x * 32, by = blockIdx.y * 32;
  int tx = threadIdx.x, ty = threadIdx.y;                 // 32 x 8
  for (int i = 0; i < 32; i += 8)
    tile[ty + i][tx] = W[(long)(by + ty + i) * 1024 + bx + tx];
  __syncthreads();
  for (int i = 0; i < 32; i += 8)
    dst[(long)(bx + ty + i) * 1024 + by + tx] = f2bf(tile[tx][ty + i]);
}

// ---------------------------------------------------------------------------
// gemm_bt: C[m][n] = sum_k A[m][k] * Bt[n][k]   (A, Bt bf16, lda=ldb=K)
// Base = r9 (best measured: 372.6 us total): 256x256 tile, BK=64, 1024 thr
// = 16 waves (4M x 4N), acc[4][4], 4 waves/SIMD, 2-phase counted-vmcnt
// double buffer, pinned lgkm+setprio compute.  THIS ROUND changes ONLY the
// MODE 1 epilogue: the old path stored 8 B per lane at stride 4 KB (l15
// spans do-rows; vT rows are 2048 u16 apart) -> ~4M scattered 8B stores,
// 2x write amplification (WRITE_SIZE 67 MB for a 32 MB output), ~40 us
// penalty (MODE1 = half the FLOP of MODE0 yet same 84 us duration).
// New MODE 1 epilogue: per-wave LDS transpose. After the K-loop's final
// barrier the 128 KB LDS is dead; each wave owns a private 8 KB region
// (waves 0-7 in As, 8-15 in Bs; no cross-wave sync). Write phase: 16x 8B
// ds_writes at dl*64 + ((tc^(dl&7))<<3) + (quad&1)*4  (2-way/quarter =
// free, m136). Read phase: 8 passes of b128 at r*64 + ((cl^(r&7))<<3)
// (2-way/quarter = free) + 16B global store, 8-lane 128B-contiguous
// segments -> full cache lines.
// MODE 0: merged q|k projection; MODE 1: vT (LDS-transposed stores);
// MODE 2: exp+rowsum; MODE 3: fp32 / lsum[row].
#define BM 256
#define BN 256
#define BK 64

template <int MODE, int GN>
__global__ __launch_bounds__(1024, 4)
void gemm_bt(const u16* __restrict__ Aall, const u16* __restrict__ Ball,
             void* __restrict__ Call, void* __restrict__ C2,
             const float* __restrict__ bias, const float* __restrict__ bias2,
             float* __restrict__ lsum,
             int M, int N, int K, long aStride, long bStride, long cStride) {
  __shared__ __align__(16) u16 As[2][BM * BK];   // 2 x 32 KB
  __shared__ __align__(16) u16 Bs[2][BN * BK];   // 2 x 32 KB

  const int z = blockIdx.z;
  const u16* A  = Aall + (long)z * aStride;
  const u16* Bt = Ball + (long)z * bStride;

  // XCD-chunked bijective swizzle, then GN grouping
  int m_idx, n_idx;
  {
    const int tiles_n = gridDim.x, tiles_m = gridDim.y;
    int nwg = tiles_n * tiles_m;
    int bid = blockIdx.y * tiles_n + blockIdx.x;
    int qq = nwg >> 3;                       // all grids are %8 == 0
    int L = (bid & 7) * qq + (bid >> 3);
    int per_group = GN * tiles_m;
    int g = L / per_group;
    int rem = L - g * per_group;
    n_idx = g * GN + rem % GN;
    m_idx = rem / GN;
  }

  const int tid  = threadIdx.x;
  const int m0   = m_idx * BM;
  const int n0   = n_idx * BN;
  const int wave = tid >> 6;             // 0..15
  const int lane = tid & 63;
  const int wm   = (wave >> 2) * 64;     // wave row offset (4 waves in M)
  const int wn   = (wave & 3) * 64;      // wave col offset (4 waves in N)
  const int l15  = lane & 15;
  const int quad = lane >> 4;

  floatx4 acc[4][4];
  floatx4 zero = {0.f, 0.f, 0.f, 0.f};
#pragma unroll
  for (int i = 0; i < 4; ++i)
#pragma unroll
    for (int j = 0; j < 4; ++j) acc[i][j] = zero;

  // LDS read offsets (u16), loop-invariant. slot = (ks*4+quad)^(r&7),
  // r&7 == l15&7 (wm,wn,mi*16 all 0 mod 8); ks1 = ks0 ^ 32 (u16).
  const int swz   = (quad ^ (l15 & 7)) * 8;
  const int aOff0 = (wm + l15) * 64 + swz;
  const int bOff0 = (wn + l15) * 64 + swz;

  // staging: unit u in {A0,A1,B0,B1}; chunk ci = u*1024+tid -> row r=ci>>3
  // (128 rows/unit), slot sc=ci&7 holds source k-chunk sc^(r&7)
  // (source-swizzle, rule #21; identical algebra to r4/r9).
  const u16* gA[2];
  const u16* gB[2];
#pragma unroll
  for (int i = 0; i < 2; ++i) {
    int ci = i * 1024 + tid;
    int r = ci >> 3, sc = ci & 7;
    int col = (sc ^ (r & 7)) * 8;
    gA[i] = A  + (long)(m0 + r) * K + col;
    gB[i] = Bt + (long)(n0 + r) * K + col;
  }

  const int nt = K / BK;            // 16 or 32 here

  // prologue: stage tile 0 -> buf0, tile 1 -> buf1; force tile 0; barrier.
  {
    u16* lA = (u16*)As + tid * 8;
    u16* lB = (u16*)Bs + tid * 8;
    GLD16(gA[0], lA); GLD16(gA[1], lA + 8192);
    GLD16(gB[0], lB); GLD16(gB[1], lB + 8192);
    GLD16(gA[0] + BK, lA + 16384); GLD16(gA[1] + BK, lA + 24576);
    GLD16(gB[0] + BK, lB + 16384); GLD16(gB[1] + BK, lB + 24576);
  }
  SB();
  asm volatile("s_waitcnt vmcnt(4)" ::: "memory");   // tile 0 landed
  SB();
  __builtin_amdgcn_s_barrier();
  SB();
#pragma unroll
  for (int i = 0; i < 2; ++i) { gA[i] += 2 * BK; gB[i] += 2 * BK; }

  for (int t = 0; t < nt; ++t) {
    const int bo  = (t & 1) << 14;                   // cur * 16384 u16 (32 KB)
    const u16* aP0 = (const u16*)As + bo + aOff0;          // ks0 base
    const u16* bP0 = (const u16*)Bs + bo + bOff0;
    const u16* aP1 = (const u16*)As + bo + (aOff0 ^ 32);   // ks1 base
    const u16* bP1 = (const u16*)Bs + bo + (bOff0 ^ 32);
    u16* ldsA = (u16*)As + bo + tid * 8;             // cur-buffer dests (t+2)
    u16* ldsB = (u16*)Bs + bo + tid * 8;
    bf16x8 af[4], bfr[4];

    // ---- phase ks0: 8 ds_reads, 16 MFMA ----
#pragma unroll
    for (int mi = 0; mi < 4; ++mi)
      af[mi] = *(const bf16x8*)(aP0 + mi * 1024);
#pragma unroll
    for (int ni = 0; ni < 4; ++ni)
      bfr[ni] = *(const bf16x8*)(bP0 + ni * 1024);
    asm volatile("s_waitcnt lgkmcnt(0)" ::: "memory");
    SB();
    __builtin_amdgcn_s_setprio(1);
#pragma unroll
    for (int mi = 0; mi < 4; ++mi)
#pragma unroll
      for (int ni = 0; ni < 4; ++ni)
        acc[mi][ni] = __builtin_amdgcn_mfma_f32_16x16x32_bf16(
            bfr[ni], af[mi], acc[mi][ni], 0, 0, 0);   // swapped operands
    __builtin_amdgcn_s_setprio(0);
    SB();

    // ---- phase ks1: 8 ds_reads, barrier, stage t+2 into cur, 16 MFMA ----
#pragma unroll
    for (int mi = 0; mi < 4; ++mi)
      af[mi] = *(const bf16x8*)(aP1 + mi * 1024);
#pragma unroll
    for (int ni = 0; ni < 4; ++ni)
      bfr[ni] = *(const bf16x8*)(bP1 + ni * 1024);
    asm volatile("s_waitcnt lgkmcnt(0)" ::: "memory");
    SB();
    __builtin_amdgcn_s_barrier();   // all waves done reading buf[cur]
    SB();
    if (t + 2 < nt) {
      GLD16(gA[0], ldsA); GLD16(gA[1], ldsA + 8192);
      GLD16(gB[0], ldsB); GLD16(gB[1], ldsB + 8192);
#pragma unroll
      for (int i = 0; i < 2; ++i) { gA[i] += BK; gB[i] += BK; }
    }
    SB();
    __builtin_amdgcn_s_setprio(1);
#pragma unroll
    for (int mi = 0; mi < 4; ++mi)
#pragma unroll
      for (int ni = 0; ni < 4; ++ni)
        acc[mi][ni] = __builtin_amdgcn_mfma_f32_16x16x32_bf16(
            bfr[ni], af[mi], acc[mi][ni], 0, 0, 0);
    __builtin_amdgcn_s_setprio(0);
    SB();
    // force tile t+1 before the barrier that opens iteration t+1
    if (t + 3 <= nt - 1)      asm volatile("s_waitcnt vmcnt(4)" ::: "memory");
    else if (t + 2 == nt - 1) asm volatile("s_waitcnt vmcnt(4)" ::: "memory");
    else if (t + 1 == nt - 1) asm volatile("s_waitcnt vmcnt(0)" ::: "memory");
    SB();
    __builtin_amdgcn_s_barrier();
    SB();
  }

  if (MODE == 1) {
    // -------- LDS-transposed vT epilogue (per-wave private 8 KB) --------
    u16* wbase = (wave < 8 ? (u16*)As : (u16*)Bs) + (wave & 7) * 4096;
    // write phase: lane's 16 x (4 bf16) chunks into transposed layout
#pragma unroll
    for (int mi = 0; mi < 4; ++mi) {
      const int dl = mi * 16 + l15;                 // local do 0..63
      const float b = bias[m0 + wm + dl];
#pragma unroll
      for (int ni = 0; ni < 4; ++ni) {
        floatx4 v = acc[mi][ni];
        int tc = ni * 2 + (quad >> 1);              // t-chunk 0..7
        int ad = dl * 64 + ((tc ^ (dl & 7)) << 3) + (quad & 1) * 4;
        uintx2 o;
        o[0] = (unsigned)f2bf(v[0] + b) | ((unsigned)f2bf(v[1] + b) << 16);
        o[1] = (unsigned)f2bf(v[2] + b) | ((unsigned)f2bf(v[3] + b) << 16);
        *(uintx2*)(wbase + ad) = o;
      }
    }
    // read phase: 8 passes, 16B/lane, 8-lane 128B-contiguous segments
    u16* C = (u16*)Call;
    const int cb0 = n0 + wn;                        // 64-aligned, one b
    const long base0 = ((long)(cb0 >> 11) * 1024) * 2048 + (cb0 & 2047);
    const int rl = lane >> 3, cl = lane & 7;
#pragma unroll
    for (int p = 0; p < 8; ++p) {
      int r = p * 8 + rl;                           // local do row
      uintx4 v = *(uintx4*)(wbase + r * 64 + ((cl ^ (r & 7)) << 3));
      *(uintx4*)(C + base0 + (long)(m0 + wm + r) * 2048 + cl * 8) = v;
    }
  } else {
  // epilogue (swapped D layout): row(m) = l15-based, 4 regs = 4 consecutive n-cols
#pragma unroll
  for (int mi = 0; mi < 4; ++mi) {
    const int row = m0 + wm + mi * 16 + l15;      // fixed per lane
    if (MODE == 2) {
      u16* C = (u16*)Call + (long)z * cStride;
      float rs = 0.f;
#pragma unroll
      for (int ni = 0; ni < 4; ++ni) {
        int colb = n0 + wn + ni * 16 + quad * 4;
        floatx4 v = acc[mi][ni];
        float e0 = __expf(v[0] * 0.03125f), e1 = __expf(v[1] * 0.03125f);
        float e2 = __expf(v[2] * 0.03125f), e3 = __expf(v[3] * 0.03125f);
        rs += (e0 + e1) + (e2 + e3);
        uintx2 o;
        o[0] = (unsigned)f2bf(e0) | ((unsigned)f2bf(e1) << 16);
        o[1] = (unsigned)f2bf(e2) | ((unsigned)f2bf(e3) << 16);
        *(uintx2*)(C + (long)row * N + colb) = o;
      }
      rs += __shfl_xor(rs, 16);
      rs += __shfl_xor(rs, 32);
      if (quad == 0) atomicAdd(lsum + (long)z * 2048 + row, rs);
    } else if (MODE == 3) {
      float* C = (float*)Call + (long)z * cStride;
      float inv = 1.0f / lsum[(long)z * 2048 + row];
#pragma unroll
      for (int ni = 0; ni < 4; ++ni) {
        int colb = n0 + wn + ni * 16 + quad * 4;
        floatx4 v = acc[mi][ni];
        floatx4 o = {v[0] * inv, v[1] * inv, v[2] * inv, v[3] * inv};
        *(floatx4*)(C + (long)row * N + colb) = o;
      }
    } else {  // MODE 0
#pragma unroll
      for (int ni = 0; ni < 4; ++ni) {
        int colb = n0 + wn + ni * 16 + quad * 4;
        u16* C = (colb < 1024) ? (u16*)Call : (u16*)C2;
        const float* bp = (colb < 1024) ? bias + colb : bias2 + (colb - 1024);
        floatx4 b = *(const floatx4*)bp;
        floatx4 v = acc[mi][ni];
        uintx2 o;
        o[0] = (unsigned)f2bf(v[0] + b[0]) | ((unsigned)f2bf(v[1] + b[1]) << 16);
        o[1] = (unsigned)f2bf(v[2] + b[2]) | ((unsigned)f2bf(v[3] + b[3]) << 16);
        *(uintx2*)(C + (long)row * 1024 + (colb & 1023)) = o;
      }
    }
  }
  }
}

// ---------------------------------------------------------------------------
extern "C" void kernel_launch(void* const* d_in, const int* in_sizes, int n_in,
                              void* d_out, int out_size, void* d_ws, size_t ws_size,
                              hipStream_t stream) {
  const float* x  = (const float*)d_in[0];
  const float* Wq = (const float*)d_in[1];
  const float* bq = (const float*)d_in[2];
  const float* Wk = (const float*)d_in[3];
  const float* bk = (const float*)d_in[4];
  const float* Wv = (const float*)d_in[5];
  const float* bv = (const float*)d_in[6];
  float* out = (float*)d_out;

  const long BT = 16384;   // B*T
  u16* xb = (u16*)d_ws;                    // [16384,1024] bf16   32 MB
  u16* WT = xb + BT * 1024;                // [3][1024,1024]       6 MB
  u16* qb = WT + 3L * 1024 * 1024;         // [16384,1024]        32 MB
  u16* kb = qb + BT * 1024;                // [16384,1024]        32 MB
  u16* vT = kb + BT * 1024;                // [8][1024][2048]     32 MB
  u16* S  = vT + BT * 1024;                // [8][2048][2048]     64 MB
  float* lsum = (float*)(S + 8L * 2048 * 2048);   // [8][2048]    64 KB

  hipMemsetAsync(lsum, 0, 8 * 2048 * sizeof(float), stream);

  // z 0..2: transpose-cast W; z 3..10: cast x
  prep_kernel<<<dim3(32, 32, 11), dim3(32, 8), 0, stream>>>(x, Wq, Wk, Wv, xb, WT);

  // q|k = x [Wq|Wk] + [bq|bk]   (WT rows 0..2047 are Wq^T then Wk^T)
  gemm_bt<0, 8><<<dim3(8, 64, 1), 1024, 0, stream>>>(
      xb, WT, qb, kb, bq, bk, nullptr, 16384, 2048, 1024, 0, 0, 0);
  // vT[b][do][t] = (Wv^T x^T + bv) : A=WvT [1024,1024], Bt=xb [16384,1024]
  gemm_bt<1, 8><<<dim3(64, 4, 1), 1024, 0, stream>>>(
      WT + 2L * 1024 * 1024, xb, vT, nullptr, bv, nullptr, nullptr,
      1024, 16384, 1024, 0, 0, 0);
  // E[b] = exp(q_b k_b^T / 32), row-sums -> lsum
  gemm_bt<2, 8><<<dim3(8, 8, 8), 1024, 0, stream>>>(
      qb, kb, S, nullptr, nullptr, nullptr, lsum,
      2048, 2048, 1024, 2048L * 1024, 2048L * 1024, 2048L * 2048);
  // out[b] = (E_b V_b) / lsum : A=E [2048,2048], Bt=vT_b [1024,2048]
  gemm_bt<3, 4><<<dim3(4, 8, 8), 1024, 0, stream>>>(
      S, vT, out, nullptr, nullptr, nullptr, lsum,
      2048, 1024, 2048, 2048L * 2048, 1024L * 2048, 2048L * 1024);
}